// Round 1
// baseline (2259.220 us; speedup 1.0000x reference)
//
#include <hip/hip_runtime.h>
#include <hip/hip_bf16.h>

#define NG 50000
#define NU 200000
#define DIM 128
#define NNZ 2000000
#define LAYERS 3

// ---------------- preprocessing: histogram + scan + counting-sort scatter ----

__global__ __launch_bounds__(256) void k_hist(const int* __restrict__ rows,
                                              const int* __restrict__ cols,
                                              int* __restrict__ row_ptr,
                                              int* __restrict__ col_ptr, int nnz) {
    int e = blockIdx.x * 256 + threadIdx.x;
    if (e < nnz) {
        atomicAdd(&row_ptr[rows[e] + 1], 1);
        atomicAdd(&col_ptr[cols[e] + 1], 1);
    }
}

// inclusive scan, 256 per block; partials[b] = block total
__global__ __launch_bounds__(256) void k_scan1(int* __restrict__ a, int n,
                                               int* __restrict__ partials) {
    __shared__ int s[256];
    int t = threadIdx.x;
    int i = blockIdx.x * 256 + t;
    s[t] = (i < n) ? a[i] : 0;
    __syncthreads();
    for (int off = 1; off < 256; off <<= 1) {
        int x = (t >= off) ? s[t - off] : 0;
        __syncthreads();
        s[t] += x;
        __syncthreads();
    }
    if (i < n) a[i] = s[t];
    if (t == 255) partials[blockIdx.x] = s[255];
}

__global__ __launch_bounds__(1024) void k_scan2(int* __restrict__ partials, int nb) {
    __shared__ int s[1024];
    int t = threadIdx.x;
    s[t] = (t < nb) ? partials[t] : 0;
    __syncthreads();
    for (int off = 1; off < 1024; off <<= 1) {
        int x = (t >= off) ? s[t - off] : 0;
        __syncthreads();
        s[t] += x;
        __syncthreads();
    }
    if (t < nb) partials[t] = s[t];
}

__global__ __launch_bounds__(256) void k_scan3(int* __restrict__ a, int n,
                                               const int* __restrict__ partials) {
    int b = blockIdx.x;
    if (b == 0) return;
    int i = b * 256 + threadIdx.x;
    if (i < n) a[i] += partials[b - 1];
}

__global__ __launch_bounds__(256) void k_scatter(const int* __restrict__ rows,
                                                 const int* __restrict__ cols,
                                                 const float* __restrict__ vals,
                                                 int* __restrict__ row_pos,
                                                 int* __restrict__ col_pos,
                                                 int* __restrict__ r_cols,
                                                 float* __restrict__ r_vals,
                                                 int* __restrict__ c_rows,
                                                 float* __restrict__ c_vals, int nnz) {
    int e = blockIdx.x * 256 + threadIdx.x;
    if (e < nnz) {
        int r = rows[e], c = cols[e];
        float v = vals[e];
        int p = atomicAdd(&row_pos[r], 1);
        r_cols[p] = c;
        r_vals[p] = v;
        int q = atomicAdd(&col_pos[c], 1);
        c_rows[q] = r;
        c_vals[q] = v;
    }
}

// ---------------- SpMM: node_msg[g] = sum_e vals[e] * user[cols[e]] ----------

__global__ __launch_bounds__(128) void k_spmm_rows(const int* __restrict__ row_ptr,
                                                   const int* __restrict__ r_cols,
                                                   const float* __restrict__ r_vals,
                                                   const float* __restrict__ x,
                                                   float* __restrict__ out) {
    int g = blockIdx.x;
    int t = threadIdx.x;
    int beg = row_ptr[g], end = row_ptr[g + 1];
    __shared__ int s_col[128];
    __shared__ float s_val[128];
    float acc = 0.f;
    for (int base = beg; base < end; base += 128) {
        int n = min(128, end - base);
        if (t < n) {
            s_col[t] = r_cols[base + t];
            s_val[t] = r_vals[base + t];
        }
        __syncthreads();
        for (int j = 0; j < n; j++)
            acc += s_val[j] * x[s_col[j] * DIM + t];
        __syncthreads();
    }
    out[g * DIM + t] = acc;
}

// ---------------- SpMM^T: user_new[u] = sum vals * msg[rows]; node_sum += ----

__global__ __launch_bounds__(128) void k_spmm_cols(const int* __restrict__ col_ptr,
                                                   const int* __restrict__ c_rows,
                                                   const float* __restrict__ c_vals,
                                                   const float* __restrict__ msg,
                                                   float* u_out,
                                                   float* __restrict__ node_sum) {
    int u = blockIdx.x;
    int t = threadIdx.x;
    int beg = col_ptr[u], end = col_ptr[u + 1];
    __shared__ int s_r[128];
    __shared__ float s_v[128];
    float acc = 0.f;
    for (int base = beg; base < end; base += 128) {
        int n = min(128, end - base);
        if (t < n) {
            s_r[t] = c_rows[base + t];
            s_v[t] = c_vals[base + t];
        }
        __syncthreads();
        for (int j = 0; j < n; j++)
            acc += s_v[j] * msg[s_r[j] * DIM + t];
        __syncthreads();
    }
    int idx = u * DIM + t;
    u_out[idx] = acc;
    node_sum[idx] += acc;
}

// ---- gated GEMM: msg = concat(nm, nm*grp) @ W + b ; edge_sum += msg ---------
// block = 256 threads, 64 group rows per block, 4 K-chunks of 64.
// NOTE: group_cur and msg_out may alias (each block reads only its own rows,
// all reads happen before the epilogue write) -> no __restrict__ on those.

__global__ __launch_bounds__(256) void k_gemm_gate(const float* __restrict__ node_msg,
                                                   const float* group_cur,
                                                   const float* __restrict__ W,
                                                   const float* __restrict__ bias,
                                                   float* msg_out,
                                                   float* __restrict__ edge_sum, int ng) {
    __shared__ float Ws[64][128];
    __shared__ float Xs[64][64];
    int t = threadIdx.x;
    int col = t & 127;
    int rhalf = t >> 7;  // 0 or 1
    int g0 = blockIdx.x * 64;

    float acc[32];
#pragma unroll
    for (int r = 0; r < 32; r++) acc[r] = 0.f;

    for (int kc = 0; kc < 4; kc++) {
        int k0 = kc * 64;
        // W chunk: rows [k0, k0+64) x 128 cols
        for (int i = t; i < 64 * 128; i += 256)
            Ws[i >> 7][i & 127] = W[(k0 + (i >> 7)) * 128 + (i & 127)];
        // X chunk: 64 rows x 64 k (gate computed inline)
        for (int i = t; i < 64 * 64; i += 256) {
            int r = i >> 6;
            int k = k0 + (i & 63);
            int g = g0 + r;
            float v = 0.f;
            if (g < ng) {
                if (k < 128) v = node_msg[g * DIM + k];
                else {
                    int kk = k - 128;
                    v = node_msg[g * DIM + kk] * group_cur[g * DIM + kk];
                }
            }
            Xs[r][i & 63] = v;
        }
        __syncthreads();
        for (int k = 0; k < 64; k++) {
            float w = Ws[k][col];
#pragma unroll
            for (int r = 0; r < 32; r++)
                acc[r] += Xs[2 * r + rhalf][k] * w;
        }
        __syncthreads();
    }

    float b = bias[col];
#pragma unroll
    for (int r = 0; r < 32; r++) {
        int g = g0 + 2 * r + rhalf;
        if (g < ng) {
            float v = acc[r] + b;
            msg_out[g * DIM + col] = v;
            edge_sum[g * DIM + col] += v;
        }
    }
}

// ---------------------------------------------------------------------------

extern "C" void kernel_launch(void* const* d_in, const int* in_sizes, int n_in,
                              void* d_out, int out_size, void* d_ws, size_t ws_size,
                              hipStream_t stream) {
    const float* group_emb = (const float*)d_in[0];  // [NG,128]
    const float* user_emb  = (const float*)d_in[1];  // [NU,128]
    const int*   rows      = (const int*)d_in[2];    // [NNZ]
    const int*   cols      = (const int*)d_in[3];    // [NNZ]
    const float* vals      = (const float*)d_in[4];  // [NNZ]
    const float* Ws        = (const float*)d_in[5];  // [3,256,128]
    const float* bs        = (const float*)d_in[6];  // [3,128]

    float* node_sum = (float*)d_out;                 // [NU,128]
    float* edge_sum = (float*)d_out + (size_t)NU * DIM;  // [NG,128]

    // workspace carve (16B aligned)
    char* p = (char*)d_ws;
    auto carve = [&](size_t bytes) {
        void* r = (void*)p;
        p += (bytes + 15) & ~(size_t)15;
        return r;
    };
    float* U        = (float*)carve((size_t)NU * DIM * 4);   // user ping buffer
    float* M        = (float*)carve((size_t)NG * DIM * 4);   // msg buffer
    float* node_msg = (float*)carve((size_t)NG * DIM * 4);
    int*   row_ptr  = (int*)carve((NG + 1) * 4);
    int*   col_ptr  = (int*)carve((NU + 1) * 4);
    int*   row_pos  = (int*)carve(NG * 4);
    int*   col_pos  = (int*)carve(NU * 4);
    int*   r_cols   = (int*)carve((size_t)NNZ * 4);
    float* r_vals   = (float*)carve((size_t)NNZ * 4);
    int*   c_rows   = (int*)carve((size_t)NNZ * 4);
    float* c_vals   = (float*)carve((size_t)NNZ * 4);
    int*   partials = (int*)carve(1024 * 4);

    // --- build CSR (row-sorted) and CSC (col-sorted) edge lists ---
    hipMemsetAsync(row_ptr, 0, (NG + 1) * 4, stream);
    hipMemsetAsync(col_ptr, 0, (NU + 1) * 4, stream);

    k_hist<<<(NNZ + 255) / 256, 256, 0, stream>>>(rows, cols, row_ptr, col_ptr, NNZ);

    {   // scan row_ptr (n = NG+1)
        int n = NG + 1, nb = (n + 255) / 256;
        k_scan1<<<nb, 256, 0, stream>>>(row_ptr, n, partials);
        k_scan2<<<1, 1024, 0, stream>>>(partials, nb);
        k_scan3<<<nb, 256, 0, stream>>>(row_ptr, n, partials);
    }
    {   // scan col_ptr (n = NU+1)
        int n = NU + 1, nb = (n + 255) / 256;
        k_scan1<<<nb, 256, 0, stream>>>(col_ptr, n, partials);
        k_scan2<<<1, 1024, 0, stream>>>(partials, nb);
        k_scan3<<<nb, 256, 0, stream>>>(col_ptr, n, partials);
    }

    hipMemcpyAsync(row_pos, row_ptr, NG * 4, hipMemcpyDeviceToDevice, stream);
    hipMemcpyAsync(col_pos, col_ptr, NU * 4, hipMemcpyDeviceToDevice, stream);

    k_scatter<<<(NNZ + 255) / 256, 256, 0, stream>>>(rows, cols, vals, row_pos, col_pos,
                                                     r_cols, r_vals, c_rows, c_vals, NNZ);

    // --- init running sums ---
    hipMemcpyAsync(node_sum, user_emb, (size_t)NU * DIM * 4, hipMemcpyDeviceToDevice, stream);
    hipMemcpyAsync(edge_sum, group_emb, (size_t)NG * DIM * 4, hipMemcpyDeviceToDevice, stream);

    // --- layers ---
    for (int l = 0; l < LAYERS; l++) {
        const float* u_in = (l == 0) ? user_emb : U;
        const float* g_in = (l == 0) ? group_emb : M;

        k_spmm_rows<<<NG, 128, 0, stream>>>(row_ptr, r_cols, r_vals, u_in, node_msg);

        k_gemm_gate<<<(NG + 63) / 64, 256, 0, stream>>>(
            node_msg, g_in, Ws + (size_t)l * 256 * 128, bs + (size_t)l * 128,
            M, edge_sum, NG);

        k_spmm_cols<<<NU, 128, 0, stream>>>(col_ptr, c_rows, c_vals, M, U, node_sum);
    }
}

// Round 2
// 2156.441 us; speedup vs baseline: 1.0477x; 1.0477x over previous
//
#include <hip/hip_runtime.h>
#include <hip/hip_bf16.h>

#define NG 50000
#define NU 200000
#define DIM 128
#define NNZ 2000000
#define LAYERS 3

// ---------------- preprocessing: histogram + scan + counting-sort scatter ----

__global__ __launch_bounds__(256) void k_hist(const int* __restrict__ rows,
                                              const int* __restrict__ cols,
                                              int* __restrict__ row_ptr,
                                              int* __restrict__ col_ptr, int nnz) {
    int e = blockIdx.x * 256 + threadIdx.x;
    if (e < nnz) {
        atomicAdd(&row_ptr[rows[e] + 1], 1);
        atomicAdd(&col_ptr[cols[e] + 1], 1);
    }
}

// inclusive scan, 256 per block; partials[b] = block total
__global__ __launch_bounds__(256) void k_scan1(int* __restrict__ a, int n,
                                               int* __restrict__ partials) {
    __shared__ int s[256];
    int t = threadIdx.x;
    int i = blockIdx.x * 256 + t;
    s[t] = (i < n) ? a[i] : 0;
    __syncthreads();
    for (int off = 1; off < 256; off <<= 1) {
        int x = (t >= off) ? s[t - off] : 0;
        __syncthreads();
        s[t] += x;
        __syncthreads();
    }
    if (i < n) a[i] = s[t];
    if (t == 255) partials[blockIdx.x] = s[255];
}

__global__ __launch_bounds__(1024) void k_scan2(int* __restrict__ partials, int nb) {
    __shared__ int s[1024];
    int t = threadIdx.x;
    s[t] = (t < nb) ? partials[t] : 0;
    __syncthreads();
    for (int off = 1; off < 1024; off <<= 1) {
        int x = (t >= off) ? s[t - off] : 0;
        __syncthreads();
        s[t] += x;
        __syncthreads();
    }
    if (t < nb) partials[t] = s[t];
}

__global__ __launch_bounds__(256) void k_scan3(int* __restrict__ a, int n,
                                               const int* __restrict__ partials) {
    int b = blockIdx.x;
    if (b == 0) return;
    int i = b * 256 + threadIdx.x;
    if (i < n) a[i] += partials[b - 1];
}

// packed edge: .x = partner index, .y = float bits of val (one 8B store per list)
__global__ __launch_bounds__(256) void k_scatter(const int* __restrict__ rows,
                                                 const int* __restrict__ cols,
                                                 const float* __restrict__ vals,
                                                 int* __restrict__ row_pos,
                                                 int* __restrict__ col_pos,
                                                 int2* __restrict__ r_edges,
                                                 int2* __restrict__ c_edges, int nnz) {
    int e = blockIdx.x * 256 + threadIdx.x;
    if (e < nnz) {
        int r = rows[e], c = cols[e];
        int vbits = __float_as_int(vals[e]);
        int p = atomicAdd(&row_pos[r], 1);
        r_edges[p] = make_int2(c, vbits);
        int q = atomicAdd(&col_pos[c], 1);
        c_edges[q] = make_int2(r, vbits);
    }
}

// ---------------- SpMM: one wave per output row, float2 per lane -------------
// out[w] = sum_e val[e] * x[idx[e]]   (edges grouped by w via counting sort)
// optional fused: sum_out[w] = (sum_init ? sum_init[w] : sum_out[w]) + acc

__global__ __launch_bounds__(256) void k_spmm(const int* __restrict__ ptr,
                                              const int2* __restrict__ edges,
                                              const float* __restrict__ x,
                                              float* __restrict__ out,
                                              const float* __restrict__ sum_init,
                                              float* __restrict__ sum_out,
                                              int nrows) {
    int w = blockIdx.x * 4 + (threadIdx.x >> 6);
    int lane = threadIdx.x & 63;
    if (w >= nrows) return;
    int beg = ptr[w], end = ptr[w + 1];
    float a0 = 0.f, a1 = 0.f;
    for (int base = beg; base < end; base += 64) {
        int n = end - base;
        if (n > 64) n = 64;
        int2 e = make_int2(0, 0);
        if (lane < n) e = edges[base + lane];
        int j = 0;
        for (; j + 4 <= n; j += 4) {
            int c0 = __shfl(e.x, j);     float v0 = __int_as_float(__shfl(e.y, j));
            int c1 = __shfl(e.x, j + 1); float v1 = __int_as_float(__shfl(e.y, j + 1));
            int c2 = __shfl(e.x, j + 2); float v2 = __int_as_float(__shfl(e.y, j + 2));
            int c3 = __shfl(e.x, j + 3); float v3 = __int_as_float(__shfl(e.y, j + 3));
            float2 x0 = *((const float2*)(x + (size_t)c0 * DIM) + lane);
            float2 x1 = *((const float2*)(x + (size_t)c1 * DIM) + lane);
            float2 x2 = *((const float2*)(x + (size_t)c2 * DIM) + lane);
            float2 x3 = *((const float2*)(x + (size_t)c3 * DIM) + lane);
            a0 += v0 * x0.x; a1 += v0 * x0.y;
            a0 += v1 * x1.x; a1 += v1 * x1.y;
            a0 += v2 * x2.x; a1 += v2 * x2.y;
            a0 += v3 * x3.x; a1 += v3 * x3.y;
        }
        for (; j < n; j++) {
            int c = __shfl(e.x, j);
            float v = __int_as_float(__shfl(e.y, j));
            float2 xv = *((const float2*)(x + (size_t)c * DIM) + lane);
            a0 += v * xv.x; a1 += v * xv.y;
        }
    }
    size_t o2 = (size_t)w * (DIM / 2) + lane;  // float2 index
    if (out) ((float2*)out)[o2] = make_float2(a0, a1);
    if (sum_out) {
        float2 s;
        if (sum_init) s = ((const float2*)sum_init)[o2];
        else          s = ((const float2*)sum_out)[o2];
        s.x += a0;
        s.y += a1;
        ((float2*)sum_out)[o2] = s;
    }
}

// ---- gated GEMM: msg = concat(nm, nm*grp) @ W + b ;
//      edge_sum = (edge_init ? edge_init : edge_sum) + msg ---------------------
// block = 256 threads, 64 group rows per block, 4 K-chunks of 64.
// NOTE: group_cur and msg_out may alias (each block reads only its own rows,
// all reads happen before the epilogue write) -> no __restrict__ on those.

__global__ __launch_bounds__(256) void k_gemm_gate(const float* __restrict__ node_msg,
                                                   const float* group_cur,
                                                   const float* __restrict__ W,
                                                   const float* __restrict__ bias,
                                                   float* msg_out,
                                                   const float* __restrict__ edge_init,
                                                   float* __restrict__ edge_sum, int ng) {
    __shared__ float Ws[64][128];
    __shared__ float Xs[64][64];
    int t = threadIdx.x;
    int col = t & 127;
    int rhalf = t >> 7;  // 0 or 1
    int g0 = blockIdx.x * 64;

    float acc[32];
#pragma unroll
    for (int r = 0; r < 32; r++) acc[r] = 0.f;

    for (int kc = 0; kc < 4; kc++) {
        int k0 = kc * 64;
        // W chunk: rows [k0, k0+64) x 128 cols
        for (int i = t; i < 64 * 128; i += 256)
            Ws[i >> 7][i & 127] = W[(k0 + (i >> 7)) * 128 + (i & 127)];
        // X chunk: 64 rows x 64 k (gate computed inline)
        for (int i = t; i < 64 * 64; i += 256) {
            int r = i >> 6;
            int k = k0 + (i & 63);
            int g = g0 + r;
            float v = 0.f;
            if (g < ng) {
                if (k < 128) v = node_msg[g * DIM + k];
                else {
                    int kk = k - 128;
                    v = node_msg[g * DIM + kk] * group_cur[g * DIM + kk];
                }
            }
            Xs[r][i & 63] = v;
        }
        __syncthreads();
        for (int k = 0; k < 64; k++) {
            float w = Ws[k][col];
#pragma unroll
            for (int r = 0; r < 32; r++)
                acc[r] += Xs[2 * r + rhalf][k] * w;
        }
        __syncthreads();
    }

    float b = bias[col];
#pragma unroll
    for (int r = 0; r < 32; r++) {
        int g = g0 + 2 * r + rhalf;
        if (g < ng) {
            int idx = g * DIM + col;
            float v = acc[r] + b;
            float es = edge_init ? edge_init[idx] : edge_sum[idx];
            msg_out[idx] = v;
            edge_sum[idx] = es + v;
        }
    }
}

// ---------------------------------------------------------------------------

extern "C" void kernel_launch(void* const* d_in, const int* in_sizes, int n_in,
                              void* d_out, int out_size, void* d_ws, size_t ws_size,
                              hipStream_t stream) {
    const float* group_emb = (const float*)d_in[0];  // [NG,128]
    const float* user_emb  = (const float*)d_in[1];  // [NU,128]
    const int*   rows      = (const int*)d_in[2];    // [NNZ]
    const int*   cols      = (const int*)d_in[3];    // [NNZ]
    const float* vals      = (const float*)d_in[4];  // [NNZ]
    const float* Ws        = (const float*)d_in[5];  // [3,256,128]
    const float* bs        = (const float*)d_in[6];  // [3,128]

    float* node_sum = (float*)d_out;                 // [NU,128]
    float* edge_sum = (float*)d_out + (size_t)NU * DIM;  // [NG,128]

    // workspace carve (16B aligned)
    char* p = (char*)d_ws;
    auto carve = [&](size_t bytes) {
        void* r = (void*)p;
        p += (bytes + 15) & ~(size_t)15;
        return r;
    };
    float* U        = (float*)carve((size_t)NU * DIM * 4);   // user ping buffer
    float* M        = (float*)carve((size_t)NG * DIM * 4);   // msg buffer
    float* node_msg = (float*)carve((size_t)NG * DIM * 4);
    int*   row_ptr  = (int*)carve((NG + 1) * 4);
    int*   col_ptr  = (int*)carve((NU + 1) * 4);
    int*   row_pos  = (int*)carve(NG * 4);
    int*   col_pos  = (int*)carve(NU * 4);
    int2*  r_edges  = (int2*)carve((size_t)NNZ * 8);
    int2*  c_edges  = (int2*)carve((size_t)NNZ * 8);
    int*   partials = (int*)carve(1024 * 4);

    // --- build CSR (row-sorted) and CSC (col-sorted) packed edge lists ---
    hipMemsetAsync(row_ptr, 0, (NG + 1) * 4, stream);
    hipMemsetAsync(col_ptr, 0, (NU + 1) * 4, stream);

    k_hist<<<(NNZ + 255) / 256, 256, 0, stream>>>(rows, cols, row_ptr, col_ptr, NNZ);

    {   // scan row_ptr (n = NG+1)
        int n = NG + 1, nb = (n + 255) / 256;
        k_scan1<<<nb, 256, 0, stream>>>(row_ptr, n, partials);
        k_scan2<<<1, 1024, 0, stream>>>(partials, nb);
        k_scan3<<<nb, 256, 0, stream>>>(row_ptr, n, partials);
    }
    {   // scan col_ptr (n = NU+1)
        int n = NU + 1, nb = (n + 255) / 256;
        k_scan1<<<nb, 256, 0, stream>>>(col_ptr, n, partials);
        k_scan2<<<1, 1024, 0, stream>>>(partials, nb);
        k_scan3<<<nb, 256, 0, stream>>>(col_ptr, n, partials);
    }

    hipMemcpyAsync(row_pos, row_ptr, NG * 4, hipMemcpyDeviceToDevice, stream);
    hipMemcpyAsync(col_pos, col_ptr, NU * 4, hipMemcpyDeviceToDevice, stream);

    k_scatter<<<(NNZ + 255) / 256, 256, 0, stream>>>(rows, cols, vals, row_pos, col_pos,
                                                     r_edges, c_edges, NNZ);

    // --- layers (running-sum inits fused into layer-1 epilogues) ---
    for (int l = 0; l < LAYERS; l++) {
        const float* u_in = (l == 0) ? user_emb : U;
        const float* g_in = (l == 0) ? group_emb : M;

        // node_msg = H @ u_in
        k_spmm<<<(NG + 3) / 4, 256, 0, stream>>>(row_ptr, r_edges, u_in,
                                                 node_msg, nullptr, nullptr, NG);

        // M = concat(node_msg, node_msg*g_in) @ W + b ; edge_sum (+)= M
        k_gemm_gate<<<(NG + 63) / 64, 256, 0, stream>>>(
            node_msg, g_in, Ws + (size_t)l * 256 * 128, bs + (size_t)l * 128,
            M, (l == 0) ? group_emb : nullptr, edge_sum, NG);

        // U = H^T @ M ; node_sum (+)= U   (skip dead U store in last layer)
        k_spmm<<<(NU + 3) / 4, 256, 0, stream>>>(col_ptr, c_edges, M,
                                                 (l == LAYERS - 1) ? nullptr : U,
                                                 (l == 0) ? user_emb : nullptr,
                                                 node_sum, NU);
    }
}